// Round 20
// baseline (99.206 us; speedup 1.0000x reference)
//
#include <hip/hip_runtime.h>
#include <hip/hip_bf16.h>

// InfoNCE loss, N=4096, D=1024, TEMP=0.07.
// loss = mean_i( -pos_i + lse_i ), lse over sim rows with diagonal masked.
// Fixed-max LSE (rows unit-norm -> sim <= 1/T): partials are order-independent.
// Symmetry via 128x128 tiles, upper triangle (J >= I).
//
// R20: R19 (fp8 BK=64, 16 steps, 4 blocks/CU, ring-2 32 KiB, counted
// vmcnt(4), plane-store epilogue) with:
//  (1) fragment-linear LDS layout: slot = [4 rb][32 rows][4 w x 16B], content
//      k16 = w ^ (row&3). Frag reads hit <=2-way banks (free) in every
//      8-lane phase; staging dest linear, source carries the inverse perm.
//  (2) reduce_finalize widened 32 -> 256 blocks (32 rows x 8 plane-groups).

typedef __attribute__((ext_vector_type(4))) int i32x4;
typedef __attribute__((ext_vector_type(8))) int i32x8;
typedef __attribute__((ext_vector_type(16))) float f32x16;

#define NN 4096
#define TWO_N 8192
#define DIM 1024
#define TEMP_INV 14.285714285714286f
#define EXP_SCALE 20.609929155566303f /* log2(e)/0.07 */
#define NT 64     /* tiles of 128 per dim */
#define NBLK 2080 /* 64*65/2 upper-tri tiles; 2080 % 8 == 0 -> bijective */
#define SLOTB 16384 /* bytes per slot: A[128][64] + B[128][64] */

#define GLD16(g, l)                                                          \
  __builtin_amdgcn_global_load_lds(                                          \
      (const __attribute__((address_space(1))) void*)(g),                    \
      (__attribute__((address_space(3))) void*)(l), 16, 0, 0)

// Fused: fp32->fp8(e4m3) cast of z=[z1;z2] AND pos=dot(z1,z2)/T in fp32.
// (Verified R6/R19: absmax 0.0 at threshold 0.1825.)
__global__ __launch_bounds__(256) void prep_kernel(
    const float* __restrict__ z1, const float* __restrict__ z2,
    unsigned int* __restrict__ zf8, float* __restrict__ pos) {
  const int row = blockIdx.x, t = threadIdx.x;
  float4 a = ((const float4*)(z1 + (size_t)row * DIM))[t];
  float4 b = ((const float4*)(z2 + (size_t)row * DIM))[t];
  int wa = __builtin_amdgcn_cvt_pk_fp8_f32(a.x, a.y, 0, false);
  wa = __builtin_amdgcn_cvt_pk_fp8_f32(a.z, a.w, wa, true);
  int wb = __builtin_amdgcn_cvt_pk_fp8_f32(b.x, b.y, 0, false);
  wb = __builtin_amdgcn_cvt_pk_fp8_f32(b.z, b.w, wb, true);
  zf8[(size_t)row * (DIM / 4) + t] = (unsigned int)wa;
  zf8[(size_t)(NN + row) * (DIM / 4) + t] = (unsigned int)wb;
  float s = a.x * b.x + a.y * b.y + a.z * b.z + a.w * b.w;
#pragma unroll
  for (int off = 1; off < 64; off <<= 1) s += __shfl_xor(s, off);
  __shared__ float tmp[4];
  if ((t & 63) == 0) tmp[t >> 6] = s;
  __syncthreads();
  if (t == 0) pos[row] = (tmp[0] + tmp[1] + tmp[2] + tmp[3]) * TEMP_INV;
}

__global__ __launch_bounds__(256, 4) void lse_kernel(
    const unsigned char* __restrict__ zb8, float* __restrict__ part) {
  __shared__ unsigned char lds[2 * SLOTB];  // 32 KiB; 4 blocks/CU = 128 KiB
  // ---- tile decode: XCD swizzle -> upper-tri (I, J), J >= I ----
  int u = ((int)blockIdx.x & 7) * (NBLK / 8) + ((int)blockIdx.x >> 3);
  int I = 0, rem = u;
  while (rem >= NT - I) { rem -= NT - I; ++I; }
  const int J = I + rem;
  const int rowA0 = I * 128, colB0 = J * 128;
  const bool diag = (I == J);

  const int t = threadIdx.x;
  const int wave = t >> 6, lane = t & 63;
  const int wm = wave >> 1, wn = wave & 1;  // 2x2 waves, each 64x64 out
  const int l31 = lane & 31, kh = lane >> 5;

  // ---- staging (fragment-linear layout) ----
  // Slot region (A at 0, B at 8192): byte off = rb*2048 + l*64 + w*16,
  // content = row (rb*32+l), k16-index (w ^ (l&3)). Chunk c = i*256 + t:
  // rb=c>>7, l=(c>>2)&31, w=c&3. Dest linear (c*16); source inverse-permuted.
  int oA[2], oB[2];
#pragma unroll
  for (int i = 0; i < 2; ++i) {
    int c = i * 256 + t, rb = c >> 7, l = (c >> 2) & 31, w = c & 3;
    int kk = w ^ (l & 3);
    oA[i] = (rowA0 + rb * 32 + l) * DIM + kk * 16;
    oB[i] = (colB0 + rb * 32 + l) * DIM + kk * 16;
  }

  const int lrow64 = l31 * 64;   // row offset within rb-block
  const int cls = l31 & 3;       // read-side XOR class
  const int x2kh = 2 * kh;

  f32x16 acc[2][2];
#pragma unroll
  for (int m = 0; m < 2; ++m)
#pragma unroll
    for (int n = 0; n < 2; ++n)
#pragma unroll
      for (int r = 0; r < 16; ++r) acc[m][n][r] = 0.f;

#define STAGE(dst_, k_)                                                       \
  {                                                                           \
    const unsigned char* gk = zb8 + ((k_) & 15) * 64;                         \
    GLD16(gk + oA[0], (dst_) + wave * 1024);                                  \
    GLD16(gk + oA[1], (dst_) + 4096 + wave * 1024);                           \
    GLD16(gk + oB[0], (dst_) + 8192 + wave * 1024);                           \
    GLD16(gk + oB[1], (dst_) + 12288 + wave * 1024);                          \
  }

  // Read one 32x64 fp8 fragment: lane reads 32 B of row (rb*32 + l31) at
  // logical k16 groups {2kh, 2kh+1}; phys w = g ^ (l31&3).
#define READ_FRAG(F, base_, rb_)                                              \
  {                                                                           \
    const unsigned char* p_ = (base_) + (rb_) * 2048 + lrow64;                \
    i32x4 lo_ = *(const i32x4*)(p_ + ((x2kh ^ cls) << 4));                    \
    i32x4 hi_ = *(const i32x4*)(p_ + (((x2kh + 1) ^ cls) << 4));              \
    F[0] = lo_[0]; F[1] = lo_[1]; F[2] = lo_[2]; F[3] = lo_[3];               \
    F[4] = hi_[0]; F[5] = hi_[1]; F[6] = hi_[2]; F[7] = hi_[3];               \
  }

  unsigned char* cur = lds;          // slot holding tile s
  unsigned char* oth = lds + SLOTB;  // stage target (tile s+1)

  STAGE(cur, 0);
  asm volatile("s_waitcnt vmcnt(0)" ::: "memory");  // own slot-0 loads done

#pragma unroll 1
  for (int s = 0; s < DIM / 64; ++s) {
    __builtin_amdgcn_s_barrier();  // BAR_A: all waves done reading oth (s-1)
    __builtin_amdgcn_sched_barrier(0);
    STAGE(oth, s + 1);             // s=15: dummy wrap (k&15=0), never read
    asm volatile("s_waitcnt vmcnt(4)" ::: "memory");  // own slot-s loads done
    __builtin_amdgcn_s_barrier();  // BAR_B: slot s published across waves
    __builtin_amdgcn_sched_barrier(0);

    i32x8 a0, a1, b0, b1;
    READ_FRAG(a0, cur, wm * 2);
    READ_FRAG(a1, cur, wm * 2 + 1);
    READ_FRAG(b0, cur + 8192, wn * 2);
    READ_FRAG(b1, cur + 8192, wn * 2 + 1);
    __builtin_amdgcn_s_setprio(1);
    acc[0][0] = __builtin_amdgcn_mfma_scale_f32_32x32x64_f8f6f4(
        a0, b0, acc[0][0], 0, 0, 0, 127, 0, 127);
    acc[0][1] = __builtin_amdgcn_mfma_scale_f32_32x32x64_f8f6f4(
        a0, b1, acc[0][1], 0, 0, 0, 127, 0, 127);
    acc[1][0] = __builtin_amdgcn_mfma_scale_f32_32x32x64_f8f6f4(
        a1, b0, acc[1][0], 0, 0, 0, 127, 0, 127);
    acc[1][1] = __builtin_amdgcn_mfma_scale_f32_32x32x64_f8f6f4(
        a1, b1, acc[1][1], 0, 0, 0, 127, 0, 127);
    __builtin_amdgcn_s_setprio(0);
    unsigned char* tmp_ = cur; cur = oth; oth = tmp_;  // swap buffers
  }
  asm volatile("s_waitcnt vmcnt(0) lgkmcnt(0)" ::: "memory");  // drain dummy

  // ---- epilogue: e=exp((dot-1)/T), diag masked; row/col partial sums ----
  // C/D 32x32: col = lane&31, row = (reg&3) + 8*(reg>>2) + 4*(lane>>5)
  // (verified R6/R17/R19). Plane stores: row partials keyed (J,wn) ->
  // planes 0..127; col partials keyed (I,wm) -> planes 128..255.
  float* rplane = part + (size_t)(2 * J + wn) * TWO_N;
  float* cplane = part + (size_t)(128 + 2 * I + wm) * TWO_N;
  float csum[2] = {0.f, 0.f};
#pragma unroll
  for (int m = 0; m < 2; ++m) {
#pragma unroll
    for (int r = 0; r < 16; ++r) {
      const int grow = rowA0 + wm * 64 + m * 32 + (r & 3) + 8 * (r >> 2) + 4 * kh;
      float s = 0.f;
#pragma unroll
      for (int n = 0; n < 2; ++n) {
        const int gcol = colB0 + wn * 64 + n * 32 + l31;
        float e = exp2f((acc[m][n][r] - 1.0f) * EXP_SCALE);
        if (grow == gcol) e = 0.f;  // mask self-similarity (diag tiles)
        s += e;
        csum[n] += e;
      }
      s += __shfl_xor(s, 1); s += __shfl_xor(s, 2); s += __shfl_xor(s, 4);
      s += __shfl_xor(s, 8); s += __shfl_xor(s, 16);
      if (l31 == 0) rplane[grow] = s;  // lanes 0,32: distinct rows (kh)
    }
  }
  if (!diag) {  // off-diagonal tiles feed transposed rows via col sums
#pragma unroll
    for (int n = 0; n < 2; ++n) {
      float c = csum[n];
      c += __shfl_xor(c, 32);  // combine kh halves (same col, disjoint rows)
      if (lane < 32) cplane[colB0 + wn * 64 + n * 32 + lane] = c;
    }
  }
#undef READ_FRAG
#undef STAGE
}

// Fold the provably-written plane entries -> per-row term -> mean.
// 256 blocks x 256 threads: block b owns rows [b*32, b*32+32); thread
// (tg = t>>5, r = t&31) sums planes [tg*32, tg*32+32) for row b*32+r.
// Valid planes for row i (Ji=i>>7): p<128 iff p>=2*Ji; p>=128 iff
// (p-128)<2*Ji (exactly 128 valid -> stale bytes never read, no memset).
__global__ __launch_bounds__(256) void reduce_finalize_kernel(
    const float* __restrict__ part, const float* __restrict__ pos,
    float* __restrict__ out) {
  const int t = threadIdx.x;
  const int tg = t >> 5, r = t & 31;
  const int i = blockIdx.x * 32 + r;
  const int Ji2 = 2 * (i >> 7);
  const float* col = part + i;
  float ssum = 0.f;
#pragma unroll 8
  for (int p = tg * 32; p < tg * 32 + 32; ++p) {
    bool valid = (p < 128) ? (p >= Ji2) : ((p - 128) < Ji2);
    if (valid) ssum += col[(size_t)p * TWO_N];
  }
  __shared__ float red[8][32];
  red[tg][r] = ssum;
  __syncthreads();
  if (t < 32) {
    float s = 0.f;
#pragma unroll
    for (int g = 0; g < 8; ++g) s += red[g][t];
    const int i2 = blockIdx.x * 32 + t;
    float term = TEMP_INV + logf(s) - pos[i2 & (NN - 1)];
    term += __shfl_xor(term, 1); term += __shfl_xor(term, 2);
    term += __shfl_xor(term, 4); term += __shfl_xor(term, 8);
    term += __shfl_xor(term, 16);
    if (t == 0) atomicAdd(out, term * (1.0f / (float)TWO_N));
  }
}

extern "C" void kernel_launch(void* const* d_in, const int* in_sizes, int n_in,
                              void* d_out, int out_size, void* d_ws, size_t ws_size,
                              hipStream_t stream) {
  const float* z1 = (const float*)d_in[0];
  const float* z2 = (const float*)d_in[1];
  float* out = (float*)d_out;

  char* ws = (char*)d_ws;
  unsigned char* zf8 = (unsigned char*)ws;             // 8 MB fp8 z
  size_t off = (size_t)TWO_N * DIM;
  float* part = (float*)(ws + off);                    // 8 MB: 256 x 8192 f32
  off += (size_t)256 * TWO_N * 4;
  float* pos = (float*)(ws + off);                     // 16 KB

  hipMemsetAsync(out, 0, sizeof(float), stream);
  prep_kernel<<<NN, 256, 0, stream>>>(z1, z2, (unsigned int*)zf8, pos);
  lse_kernel<<<NBLK, 256, 0, stream>>>(zf8, part);
  reduce_finalize_kernel<<<TWO_N / 32, 256, 0, stream>>>(part, pos, out);
}